// Round 1
// 18500.836 us; speedup vs baseline: 1.0788x; 1.0788x over previous
//
#include <hip/hip_runtime.h>

// NeuralODE SIREN (2->128->128->2, sin, w0=44), RK4 3/8-rule, 100 steps.
// Round 3: latency/occupancy restructure.
//  - Phase-1 LDS transpose ELIMINATED: each lane computes its MFMA A-fragment
//    elements directly (shfl-broadcast particle coords + per-lane W1 from LDS).
//  - Phase-3 LDS reduction ELIMINATED: DPP row_ror 16-lane reduction + owner
//    select; particle<->lane ownership permuted so results land at owners.
//  - No hot-loop LDS writes, no fences, no __syncthreads after staging.
//  - LDS 36.3 KB + __launch_bounds__(256,4): 4 blocks/CU, all 1024 blocks
//    resident in ONE round (was 2 rounds at 2 blocks/CU).
//  - Register budget 128 (4 waves/SIMD): GEMM split over N-halves
//    (acc[4][4] = 64 regs), A-chunk rebuilt per half (c-outer, 32 regs).
//    Cost: layer-1 sins x2 -- cheaper than doubling the Blo global stream.
//  - Weights prescaled by w0/(2*pi): sin input already in revolutions.
//  - Nontemporal out stores: don't evict the 32KB-hot Blo stream from L1/L2.

#define W0F    44.0f
#define INV2PI 0.15915494309189535f
#define SCALE  (W0F * INV2PI)
#define WIDTH  128
#define NPART  262144
#define TSTEPS 101

typedef short s16x8 __attribute__((ext_vector_type(8)));
typedef float f32x4 __attribute__((ext_vector_type(4)));

__device__ __forceinline__ float sin_rev(float z) {
    // sin(2*pi*z); fract is the exact periodic range reduction.
    return __builtin_amdgcn_sinf(__builtin_amdgcn_fractf(z));
}
__device__ __forceinline__ unsigned short f2bf(float x) {   // RNE f32->bf16
    __bf16 b = (__bf16)x;
    return __builtin_bit_cast(unsigned short, b);
}
__device__ __forceinline__ float bf2f(unsigned short u) {   // exact bf16->f32
    unsigned int v = ((unsigned int)u) << 16;
    return __builtin_bit_cast(float, v);
}

// ---- 16-lane (DPP row) all-lanes sum via circulant row_ror adds ----
#define ROR_ADD(x, ctrl) ((x) + __builtin_bit_cast(float, \
    __builtin_amdgcn_update_dpp(0, __builtin_bit_cast(int, (x)), (ctrl), 0xF, 0xF, false)))
__device__ __forceinline__ float row_sum16(float x) {
    x = ROR_ADD(x, 0x128);   // row_ror:8
    x = ROR_ADD(x, 0x124);   // row_ror:4
    x = ROR_ADD(x, 0x122);   // row_ror:2
    x = ROR_ADD(x, 0x121);   // row_ror:1
    return x;                // every lane holds the 16-lane sum
}

// 16-way register select (15 v_cndmask), idx = per-lane 0..15
__device__ __forceinline__ float sel16(const float g[16], int idx) {
    float a[8], b[4], c[2];
    #pragma unroll
    for (int i = 0; i < 8; ++i) a[i] = (idx & 8) ? g[i + 8] : g[i];
    #pragma unroll
    for (int i = 0; i < 4; ++i) b[i] = (idx & 4) ? a[i + 4] : a[i];
    #pragma unroll
    for (int i = 0; i < 2; ++i) c[i] = (idx & 2) ? b[i + 2] : b[i];
    return (idx & 1) ? c[1] : c[0];
}

// ws layout: shorts [0,16384) = W2-hi B-frags; shorts [16384,32768) = W2-lo
// B-frags; floats [16384,16640) = SCALE*W1; floats [16640,16768) = SCALE*b1.
// Frag index i = ((nt*4+c)*64 + lane)*8 + j  <->  B[k][n], k=32c+8*(lane>>4)+j,
// n=16*nt+(lane&15)  (mfma_f32_16x16x32_bf16 B-operand layout).
__global__ void prep_kernel(const float* __restrict__ W1, const float* __restrict__ b1,
                            const float* __restrict__ W2, float* __restrict__ ws) {
    int i = blockIdx.x * blockDim.x + threadIdx.x;
    unsigned short* whi = (unsigned short*)ws;
    unsigned short* wlo = whi + 16384;
    if (i < 16384) {
        int j = i & 7, l = (i >> 3) & 63, c = (i >> 9) & 3, nt = (i >> 11) & 7;
        int k = 32 * c + 8 * (l >> 4) + j;
        int n = 16 * nt + (l & 15);
        float v = SCALE * W2[k * WIDTH + n];
        unsigned short hi = f2bf(v);
        whi[i] = hi;
        wlo[i] = f2bf(v - bf2f(hi));
    }
    if (i < 2 * WIDTH) ws[16384 + i] = SCALE * W1[i];
    if (i < WIDTH)     ws[16384 + 256 + i] = SCALE * b1[i];
}

__launch_bounds__(256, 4)
__global__ void ode_kernel(const float* __restrict__ t,
                           const float2* __restrict__ x0,
                           const float* __restrict__ ws,
                           const float* __restrict__ W3,
                           const float* __restrict__ b2,
                           const float* __restrict__ b3,
                           float2* __restrict__ out) {
    __shared__ unsigned int sB[8192];                     // W2-hi frags, 32 KB
    __shared__ float sWx[WIDTH], sWy[WIDTH], sWb[WIDTH];  // SCALE*W1 cols + b1, 1.5 KB
    __shared__ float4 sPv[WIDTH];                         // {SCALE*b2, w3x, w3y, 0}, 2 KB

    const int tid = threadIdx.x;
    const int wave = tid >> 6;
    const int lane = tid & 63;
    const int lane15 = lane & 15;
    const int kg = lane >> 4;

    // one-time staging
    {
        const uint4* src = (const uint4*)ws;
        uint4* dst = (uint4*)sB;
        #pragma unroll
        for (int j = 0; j < 8; ++j) dst[tid + 256 * j] = src[tid + 256 * j];
    }
    if (tid < WIDTH) {
        sWx[tid] = ws[16384 + tid];
        sWy[tid] = ws[16384 + WIDTH + tid];
        sWb[tid] = ws[16384 + 256 + tid];
        sPv[tid] = make_float4(SCALE * b2[tid], W3[2 * tid], W3[2 * tid + 1], 0.f);
    }
    __syncthreads();   // the ONLY barrier; hot loop is barrier/fence-free

    const uint4* Blo = (const uint4*)(ws + 8192);   // W2-lo frags (global, L1/L2-hot)

    // Ownership permutation: lane l owns local particle
    //   m(l) = 16*(lane15>>2) + 4*kg + (lane15&3)
    // so that after the DPP reduction (which leaves row m'=16mt+4kg+r sums in
    // kg's 16-lane group), the owner's slot index is exactly lane15.
    const int mloc = 16 * (lane15 >> 2) + 4 * kg + (lane15 & 3);
    const int p = blockIdx.x * 256 + wave * 64 + mloc;

    float2 y = x0[p];
    __builtin_nontemporal_store(__builtin_bit_cast(double, y), (double*)(out + p));  // row 0

    const float b30 = b3[0], b31 = b3[1];

    float tprev = t[0];
    #pragma unroll 1
    for (int step = 0; step < TSTEPS - 1; ++step) {
        const float tnext = t[step + 1];
        const float dt = tnext - tprev;
        tprev = tnext;

        float k1x=0.f,k1y=0.f,k2x=0.f,k2y=0.f,k3x=0.f,k3y=0.f,sx=0.f,sy=0.f;

        #pragma unroll 1
        for (int s = 0; s < 4; ++s) {
            float yinx, yiny;
            if (s == 0)      { yinx = y.x;                                 yiny = y.y; }
            else if (s == 1) { const float c1 = dt * (1.0f / 3.0f);
                               yinx = y.x + c1 * k1x;                       yiny = y.y + c1 * k1y; }
            else if (s == 2) { yinx = y.x + dt * (k2x - (1.0f/3.0f) * k1x); yiny = y.y + dt * (k2y - (1.0f/3.0f) * k1y); }
            else             { yinx = y.x + dt * (k1x - k2x + k3x);         yiny = y.y + dt * (k1y - k2y + k3y); }

            // ---- f(yin) ----
            // Broadcast tile-row coords: row m' = 16*mt + lane15 is owned by
            // lane 16*(lane15>>2) + 4*mt + (lane15&3).
            float qx[4], qy[4];
            #pragma unroll
            for (int mt = 0; mt < 4; ++mt) {
                int srcl = 16 * (lane15 >> 2) + 4 * mt + (lane15 & 3);
                qx[mt] = __shfl(yinx, srcl, 64);
                qy[mt] = __shfl(yiny, srcl, 64);
            }

            float fx = b30, fy = b31;

            // GEMM over two N-halves (acc = 64 VGPRs each); A-chunk rebuilt
            // per half (c-outer) to stay inside the 128-reg/4-wave budget.
            #pragma unroll 1
            for (int ht = 0; ht < 2; ++ht) {
                f32x4 acc[4][4];
                #pragma unroll
                for (int i = 0; i < 4; ++i)
                    #pragma unroll
                    for (int j = 0; j < 4; ++j) acc[i][j] = (f32x4){0.f, 0.f, 0.f, 0.f};

                #pragma unroll 1
                for (int c = 0; c < 4; ++c) {
                    // prefetch this c's lo-B frags; latency hides under A-build
                    uint4 blU[4];
                    #pragma unroll
                    for (int ntl = 0; ntl < 4; ++ntl)
                        blU[ntl] = Blo[((4 * ht + ntl) * 4 + c) * 64 + lane];

                    // Build A-fragments in-layout: element j of frag (mt,c) is
                    // A[16mt+lane15][32c+8kg+j], pairs packed low/high.
                    unsigned int ah[4][4], al[4][4];
                    #pragma unroll
                    for (int jq = 0; jq < 2; ++jq) {
                        float4 wxv = *(const float4*)&sWx[32 * c + 8 * kg + 4 * jq];
                        float4 wyv = *(const float4*)&sWy[32 * c + 8 * kg + 4 * jq];
                        float4 wbv = *(const float4*)&sWb[32 * c + 8 * kg + 4 * jq];
                        #pragma unroll
                        for (int mt = 0; mt < 4; ++mt) {
                            float v0 = sin_rev(fmaf(qx[mt], wxv.x, fmaf(qy[mt], wyv.x, wbv.x)));
                            float v1 = sin_rev(fmaf(qx[mt], wxv.y, fmaf(qy[mt], wyv.y, wbv.y)));
                            float v2 = sin_rev(fmaf(qx[mt], wxv.z, fmaf(qy[mt], wyv.z, wbv.z)));
                            float v3 = sin_rev(fmaf(qx[mt], wxv.w, fmaf(qy[mt], wyv.w, wbv.w)));
                            unsigned short h0 = f2bf(v0), h1 = f2bf(v1);
                            unsigned short h2 = f2bf(v2), h3 = f2bf(v3);
                            ah[mt][2*jq]   = (unsigned int)h0 | ((unsigned int)h1 << 16);
                            ah[mt][2*jq+1] = (unsigned int)h2 | ((unsigned int)h3 << 16);
                            al[mt][2*jq]   = (unsigned int)f2bf(v0 - bf2f(h0)) |
                                             ((unsigned int)f2bf(v1 - bf2f(h1)) << 16);
                            al[mt][2*jq+1] = (unsigned int)f2bf(v2 - bf2f(h2)) |
                                             ((unsigned int)f2bf(v3 - bf2f(h3)) << 16);
                        }
                    }

                    #pragma unroll
                    for (int ntl = 0; ntl < 4; ++ntl) {
                        int fi = (4 * ht + ntl) * 4 + c;
                        uint4 bhU = *(const uint4*)&sB[fi * 256 + lane * 4];
                        s16x8 bh = __builtin_bit_cast(s16x8, bhU);
                        s16x8 bl = __builtin_bit_cast(s16x8, blU[ntl]);
                        #pragma unroll
                        for (int mt = 0; mt < 4; ++mt) {
                            s16x8 ahv = __builtin_bit_cast(s16x8,
                                make_uint4(ah[mt][0], ah[mt][1], ah[mt][2], ah[mt][3]));
                            s16x8 alv = __builtin_bit_cast(s16x8,
                                make_uint4(al[mt][0], al[mt][1], al[mt][2], al[mt][3]));
                            acc[ntl][mt] = __builtin_amdgcn_mfma_f32_16x16x32_bf16(ahv, bh, acc[ntl][mt], 0, 0, 0);
                            acc[ntl][mt] = __builtin_amdgcn_mfma_f32_16x16x32_bf16(alv, bh, acc[ntl][mt], 0, 0, 0);
                            acc[ntl][mt] = __builtin_amdgcn_mfma_f32_16x16x32_bf16(ahv, bl, acc[ntl][mt], 0, 0, 0);
                        }
                    }
                }

                // Epilogue: sin + layer-3 column-partials for this half.
                // C layout: value (ntl,mt,r) = row m'=16mt+4kg+r, col n=16nt+lane15.
                float gx[16], gy[16];
                #pragma unroll
                for (int i = 0; i < 16; ++i) { gx[i] = 0.f; gy[i] = 0.f; }
                #pragma unroll
                for (int ntl = 0; ntl < 4; ++ntl) {
                    float4 pv = sPv[16 * (4 * ht + ntl) + lane15];
                    #pragma unroll
                    for (int mt = 0; mt < 4; ++mt) {
                        #pragma unroll
                        for (int r = 0; r < 4; ++r) {
                            float sn = sin_rev(acc[ntl][mt][r] + pv.x);
                            gx[4*mt+r] = fmaf(sn, pv.y, gx[4*mt+r]);
                            gy[4*mt+r] = fmaf(sn, pv.z, gy[4*mt+r]);
                        }
                    }
                }
                // Reduce each slot over the 16 n-lanes (DPP, no LDS, no fences);
                // owner's slot index is exactly lane15 by construction.
                #pragma unroll
                for (int i = 0; i < 16; ++i) { gx[i] = row_sum16(gx[i]); gy[i] = row_sum16(gy[i]); }
                fx += sel16(gx, lane15);
                fy += sel16(gy, lane15);
            }
            // ---- end f ----

            if (s == 0)      { k1x = fx; k1y = fy; sx = fx;        sy = fy; }
            else if (s == 1) { k2x = fx; k2y = fy; sx += 3.f * fx; sy += 3.f * fy; }
            else if (s == 2) { k3x = fx; k3y = fy; sx += 3.f * fx; sy += 3.f * fy; }
            else             {                     sx += fx;       sy += fy; }
        }

        const float cc = dt * 0.125f;
        y.x += sx * cc;
        y.y += sy * cc;
        __builtin_nontemporal_store(__builtin_bit_cast(double, y),
                                    (double*)(out + (size_t)(step + 1) * NPART + p));
    }
}

extern "C" void kernel_launch(void* const* d_in, const int* in_sizes, int n_in,
                              void* d_out, int out_size, void* d_ws, size_t ws_size,
                              hipStream_t stream) {
    const float*  t  = (const float*)d_in[0];
    const float2* x0 = (const float2*)d_in[1];
    const float*  W1 = (const float*)d_in[2];
    const float*  b1 = (const float*)d_in[3];
    const float*  W2 = (const float*)d_in[4];
    const float*  b2 = (const float*)d_in[5];
    const float*  W3 = (const float*)d_in[6];
    const float*  b3 = (const float*)d_in[7];
    float* ws = (float*)d_ws;
    float2* out = (float2*)d_out;

    prep_kernel<<<64, 256, 0, stream>>>(W1, b1, W2, ws);
    ode_kernel<<<NPART / 256, 256, 0, stream>>>(t, x0, ws, W3, b2, b3, out);
}

// Round 2
// 13943.280 us; speedup vs baseline: 1.4315x; 1.3269x over previous
//
#include <hip/hip_runtime.h>

// NeuralODE SIREN (2->128->128->2, sin, w0=44), RK4 3/8-rule, 100 steps.
// Round 4: cut VALU issue work (the binding pipe at VALUBusy 70%).
//  - GEMM split over M-HALVES (particles), not N-halves: layer-1 A-build is
//    partitioned, not duplicated -> 128 sins + 64 bf16 pair-splits per lane
//    per f-eval (was 256 + 128). B-hi (LDS) and B-lo (L2) are re-read per
//    half instead -- nearly free at current LDS/L2 utilization.
//  - Epilogue reduction halves: gx[8]/gy[8], 32 row_sum16 (was 64), sel8.
//    Owner/broadcast lane formulas unchanged (mt'=lane15>>2, r=lane15&3,
//    half-ownership bit = lane15>>3).
//  - Plain out stores (round-3 nontemporal caused 6.7x HBM write
//    amplification: 23.6 GB vs 3.5 GB -- nt bypasses L2 write-combining).
//  - ht loop is unroll-1 with explicit scalar qx/qy selects (no
//    runtime-indexed register arrays -> no scratch).

#define W0F    44.0f
#define INV2PI 0.15915494309189535f
#define SCALE  (W0F * INV2PI)
#define WIDTH  128
#define NPART  262144
#define TSTEPS 101

typedef short s16x8 __attribute__((ext_vector_type(8)));
typedef float f32x4 __attribute__((ext_vector_type(4)));

__device__ __forceinline__ float sin_rev(float z) {
    // sin(2*pi*z); fract is the exact periodic range reduction.
    return __builtin_amdgcn_sinf(__builtin_amdgcn_fractf(z));
}
__device__ __forceinline__ unsigned short f2bf(float x) {   // RNE f32->bf16
    __bf16 b = (__bf16)x;
    return __builtin_bit_cast(unsigned short, b);
}
__device__ __forceinline__ float bf2f(unsigned short u) {   // exact bf16->f32
    unsigned int v = ((unsigned int)u) << 16;
    return __builtin_bit_cast(float, v);
}

// ---- 16-lane (DPP row) all-lanes sum via circulant row_ror adds ----
#define ROR_ADD(x, ctrl) ((x) + __builtin_bit_cast(float, \
    __builtin_amdgcn_update_dpp(0, __builtin_bit_cast(int, (x)), (ctrl), 0xF, 0xF, false)))
__device__ __forceinline__ float row_sum16(float x) {
    x = ROR_ADD(x, 0x128);   // row_ror:8
    x = ROR_ADD(x, 0x124);   // row_ror:4
    x = ROR_ADD(x, 0x122);   // row_ror:2
    x = ROR_ADD(x, 0x121);   // row_ror:1
    return x;                // every lane holds the 16-lane sum
}

// 8-way register select (7 v_cndmask), idx = per-lane 0..7
__device__ __forceinline__ float sel8(const float g[8], int idx) {
    float a[4], b[2];
    #pragma unroll
    for (int i = 0; i < 4; ++i) a[i] = (idx & 4) ? g[i + 4] : g[i];
    #pragma unroll
    for (int i = 0; i < 2; ++i) b[i] = (idx & 2) ? a[i + 2] : a[i];
    return (idx & 1) ? b[1] : b[0];
}

// ws layout: shorts [0,16384) = W2-hi B-frags; shorts [16384,32768) = W2-lo
// B-frags; floats [16384,16640) = SCALE*W1; floats [16640,16768) = SCALE*b1.
// Frag index i = ((nt*4+c)*64 + lane)*8 + j  <->  B[k][n], k=32c+8*(lane>>4)+j,
// n=16*nt+(lane&15)  (mfma_f32_16x16x32_bf16 B-operand layout).
__global__ void prep_kernel(const float* __restrict__ W1, const float* __restrict__ b1,
                            const float* __restrict__ W2, float* __restrict__ ws) {
    int i = blockIdx.x * blockDim.x + threadIdx.x;
    unsigned short* whi = (unsigned short*)ws;
    unsigned short* wlo = whi + 16384;
    if (i < 16384) {
        int j = i & 7, l = (i >> 3) & 63, c = (i >> 9) & 3, nt = (i >> 11) & 7;
        int k = 32 * c + 8 * (l >> 4) + j;
        int n = 16 * nt + (l & 15);
        float v = SCALE * W2[k * WIDTH + n];
        unsigned short hi = f2bf(v);
        whi[i] = hi;
        wlo[i] = f2bf(v - bf2f(hi));
    }
    if (i < 2 * WIDTH) ws[16384 + i] = SCALE * W1[i];
    if (i < WIDTH)     ws[16384 + 256 + i] = SCALE * b1[i];
}

__launch_bounds__(256, 4)
__global__ void ode_kernel(const float* __restrict__ t,
                           const float2* __restrict__ x0,
                           const float* __restrict__ ws,
                           const float* __restrict__ W3,
                           const float* __restrict__ b2,
                           const float* __restrict__ b3,
                           float2* __restrict__ out) {
    __shared__ unsigned int sB[8192];                     // W2-hi frags, 32 KB
    __shared__ __align__(16) float sWx[WIDTH], sWy[WIDTH], sWb[WIDTH];
    __shared__ float4 sPv[WIDTH];                         // {SCALE*b2, w3x, w3y, 0}

    const int tid = threadIdx.x;
    const int wave = tid >> 6;
    const int lane = tid & 63;
    const int lane15 = lane & 15;
    const int kg = lane >> 4;

    // one-time staging
    {
        const uint4* src = (const uint4*)ws;
        uint4* dst = (uint4*)sB;
        #pragma unroll
        for (int j = 0; j < 8; ++j) dst[tid + 256 * j] = src[tid + 256 * j];
    }
    if (tid < WIDTH) {
        sWx[tid] = ws[16384 + tid];
        sWy[tid] = ws[16384 + WIDTH + tid];
        sWb[tid] = ws[16384 + 256 + tid];
        sPv[tid] = make_float4(SCALE * b2[tid], W3[2 * tid], W3[2 * tid + 1], 0.f);
    }
    __syncthreads();   // the ONLY barrier; hot loop is barrier/fence-free

    const uint4* Blo = (const uint4*)(ws + 8192);   // W2-lo frags (global, L2-hot)

    // Ownership permutation: lane l owns local particle
    //   m(l) = 16*(lane15>>2) + 4*kg + (lane15&3)
    // so the DPP-reduced row sums land at owner lanes: owner's half bit is
    // lane15>>3, its slot in that half's gx[8] is lane&7.
    const int mloc = 16 * (lane15 >> 2) + 4 * kg + (lane15 & 3);
    const int p = blockIdx.x * 256 + wave * 64 + mloc;

    float2 y = x0[p];
    out[p] = y;   // row 0 = x0

    const float b30 = b3[0], b31 = b3[1];

    float tprev = t[0];
    #pragma unroll 1
    for (int step = 0; step < TSTEPS - 1; ++step) {
        const float tnext = t[step + 1];
        const float dt = tnext - tprev;
        tprev = tnext;

        float k1x=0.f,k1y=0.f,k2x=0.f,k2y=0.f,k3x=0.f,k3y=0.f,sx=0.f,sy=0.f;

        #pragma unroll 1
        for (int s = 0; s < 4; ++s) {
            float yinx, yiny;
            if (s == 0)      { yinx = y.x;                                 yiny = y.y; }
            else if (s == 1) { const float c1 = dt * (1.0f / 3.0f);
                               yinx = y.x + c1 * k1x;                       yiny = y.y + c1 * k1y; }
            else if (s == 2) { yinx = y.x + dt * (k2x - (1.0f/3.0f) * k1x); yiny = y.y + dt * (k2y - (1.0f/3.0f) * k1y); }
            else             { yinx = y.x + dt * (k1x - k2x + k3x);         yiny = y.y + dt * (k1y - k2y + k3y); }

            // ---- f(yin) ----
            // Broadcast tile-row coords: row m' = 16*mt + lane15 is owned by
            // lane 16*(lane15>>2) + 4*mt + (lane15&3).
            float qx0, qx1, qx2, qx3, qy0, qy1, qy2, qy3;
            {
                const int sbase = 16 * (lane15 >> 2) + (lane15 & 3);
                qx0 = __shfl(yinx, sbase,      64); qy0 = __shfl(yiny, sbase,      64);
                qx1 = __shfl(yinx, sbase + 4,  64); qy1 = __shfl(yiny, sbase + 4,  64);
                qx2 = __shfl(yinx, sbase + 8,  64); qy2 = __shfl(yiny, sbase + 8,  64);
                qx3 = __shfl(yinx, sbase + 12, 64); qy3 = __shfl(yiny, sbase + 12, 64);
            }

            float fx = b30, fy = b31;

            // GEMM over two M-halves: acc[8nt][2mt] = 64 regs; A built ONCE
            // per element (partitioned by M, no duplication).
            #pragma unroll 1
            for (int ht = 0; ht < 2; ++ht) {
                const float qxl0 = ht ? qx2 : qx0, qyl0 = ht ? qy2 : qy0;
                const float qxl1 = ht ? qx3 : qx1, qyl1 = ht ? qy3 : qy1;

                f32x4 acc[8][2];
                #pragma unroll
                for (int i = 0; i < 8; ++i)
                    #pragma unroll
                    for (int j = 0; j < 2; ++j) acc[i][j] = (f32x4){0.f, 0.f, 0.f, 0.f};

                #pragma unroll 1
                for (int c = 0; c < 4; ++c) {
                    // Build A-fragments in-layout: element j of frag (mtl,c) is
                    // A[16*(2ht+mtl)+lane15][32c+8kg+j], pairs packed low/high.
                    unsigned int ah[2][4], al[2][4];
                    #pragma unroll
                    for (int jq = 0; jq < 2; ++jq) {
                        float4 wxv = *(const float4*)&sWx[32 * c + 8 * kg + 4 * jq];
                        float4 wyv = *(const float4*)&sWy[32 * c + 8 * kg + 4 * jq];
                        float4 wbv = *(const float4*)&sWb[32 * c + 8 * kg + 4 * jq];
                        #pragma unroll
                        for (int mtl = 0; mtl < 2; ++mtl) {
                            const float qxm = mtl ? qxl1 : qxl0;
                            const float qym = mtl ? qyl1 : qyl0;
                            float v0 = sin_rev(fmaf(qxm, wxv.x, fmaf(qym, wyv.x, wbv.x)));
                            float v1 = sin_rev(fmaf(qxm, wxv.y, fmaf(qym, wyv.y, wbv.y)));
                            float v2 = sin_rev(fmaf(qxm, wxv.z, fmaf(qym, wyv.z, wbv.z)));
                            float v3 = sin_rev(fmaf(qxm, wxv.w, fmaf(qym, wyv.w, wbv.w)));
                            unsigned short h0 = f2bf(v0), h1 = f2bf(v1);
                            unsigned short h2 = f2bf(v2), h3 = f2bf(v3);
                            ah[mtl][2*jq]   = (unsigned int)h0 | ((unsigned int)h1 << 16);
                            ah[mtl][2*jq+1] = (unsigned int)h2 | ((unsigned int)h3 << 16);
                            al[mtl][2*jq]   = (unsigned int)f2bf(v0 - bf2f(h0)) |
                                              ((unsigned int)f2bf(v1 - bf2f(h1)) << 16);
                            al[mtl][2*jq+1] = (unsigned int)f2bf(v2 - bf2f(h2)) |
                                              ((unsigned int)f2bf(v3 - bf2f(h3)) << 16);
                        }
                    }

                    // Full-N sweep for this half; lo-B prefetched in 2 batches.
                    #pragma unroll
                    for (int g = 0; g < 2; ++g) {
                        uint4 blU[4];
                        #pragma unroll
                        for (int q = 0; q < 4; ++q)
                            blU[q] = Blo[((4 * g + q) * 4 + c) * 64 + lane];
                        #pragma unroll
                        for (int q = 0; q < 4; ++q) {
                            const int ntl = 4 * g + q;
                            uint4 bhU = *(const uint4*)&sB[(ntl * 4 + c) * 256 + lane * 4];
                            s16x8 bh = __builtin_bit_cast(s16x8, bhU);
                            s16x8 bl = __builtin_bit_cast(s16x8, blU[q]);
                            #pragma unroll
                            for (int mtl = 0; mtl < 2; ++mtl) {
                                s16x8 ahv = __builtin_bit_cast(s16x8,
                                    make_uint4(ah[mtl][0], ah[mtl][1], ah[mtl][2], ah[mtl][3]));
                                s16x8 alv = __builtin_bit_cast(s16x8,
                                    make_uint4(al[mtl][0], al[mtl][1], al[mtl][2], al[mtl][3]));
                                acc[ntl][mtl] = __builtin_amdgcn_mfma_f32_16x16x32_bf16(ahv, bh, acc[ntl][mtl], 0, 0, 0);
                                acc[ntl][mtl] = __builtin_amdgcn_mfma_f32_16x16x32_bf16(alv, bh, acc[ntl][mtl], 0, 0, 0);
                                acc[ntl][mtl] = __builtin_amdgcn_mfma_f32_16x16x32_bf16(ahv, bl, acc[ntl][mtl], 0, 0, 0);
                            }
                        }
                    }
                }

                // Epilogue: sin + layer-3 column partials for this M-half.
                // C layout: value (ntl,mtl,r) = row 16*(2ht+mtl)+4kg+r,
                // col n = 16*ntl + lane15.
                float gx[8], gy[8];
                #pragma unroll
                for (int i = 0; i < 8; ++i) { gx[i] = 0.f; gy[i] = 0.f; }
                #pragma unroll
                for (int ntl = 0; ntl < 8; ++ntl) {
                    float4 pv = sPv[16 * ntl + lane15];
                    #pragma unroll
                    for (int mtl = 0; mtl < 2; ++mtl) {
                        #pragma unroll
                        for (int r = 0; r < 4; ++r) {
                            float sn = sin_rev(acc[ntl][mtl][r] + pv.x);
                            gx[4*mtl+r] = fmaf(sn, pv.y, gx[4*mtl+r]);
                            gy[4*mtl+r] = fmaf(sn, pv.z, gy[4*mtl+r]);
                        }
                    }
                }
                // 16-lane n-reduction (DPP, no LDS); owner select.
                #pragma unroll
                for (int i = 0; i < 8; ++i) { gx[i] = row_sum16(gx[i]); gy[i] = row_sum16(gy[i]); }
                const float vx = sel8(gx, lane & 7);
                const float vy = sel8(gy, lane & 7);
                const bool own = ((lane15 >> 3) == ht);
                fx += own ? vx : 0.0f;
                fy += own ? vy : 0.0f;
            }
            // ---- end f ----

            if (s == 0)      { k1x = fx; k1y = fy; sx = fx;        sy = fy; }
            else if (s == 1) { k2x = fx; k2y = fy; sx += 3.f * fx; sy += 3.f * fy; }
            else if (s == 2) { k3x = fx; k3y = fy; sx += 3.f * fx; sy += 3.f * fy; }
            else             {                     sx += fx;       sy += fy; }
        }

        const float cc = dt * 0.125f;
        y.x += sx * cc;
        y.y += sy * cc;
        out[(size_t)(step + 1) * NPART + p] = y;
    }
}

extern "C" void kernel_launch(void* const* d_in, const int* in_sizes, int n_in,
                              void* d_out, int out_size, void* d_ws, size_t ws_size,
                              hipStream_t stream) {
    const float*  t  = (const float*)d_in[0];
    const float2* x0 = (const float2*)d_in[1];
    const float*  W1 = (const float*)d_in[2];
    const float*  b1 = (const float*)d_in[3];
    const float*  W2 = (const float*)d_in[4];
    const float*  b2 = (const float*)d_in[5];
    const float*  W3 = (const float*)d_in[6];
    const float*  b3 = (const float*)d_in[7];
    float* ws = (float*)d_ws;
    float2* out = (float2*)d_out;

    prep_kernel<<<64, 256, 0, stream>>>(W1, b1, W2, ws);
    ode_kernel<<<NPART / 256, 256, 0, stream>>>(t, x0, ws, W3, b2, b3, out);
}

// Round 3
// 13422.643 us; speedup vs baseline: 1.4870x; 1.0388x over previous
//
#include <hip/hip_runtime.h>

// NeuralODE SIREN (2->128->128->2, sin, w0=44), RK4 3/8-rule, 100 steps.
// Round 5: kill the hot-loop scratch spill (WRITE_SIZE 9.4 GB vs 212 MB ideal
// = ~22 dwords spilled+reloaded per f-eval under the 128-reg/4-wave budget).
// Register diet so the live set genuinely fits 128 unified regs:
//  - SCALE*b2 folded into MFMA acc INIT (read from LDS, transient): kills the
//    8 persistent b2v regs AND 128 epilogue adds per f-eval.
//  - Per-half coords re-__shfl'd inside the ht loop (-4 persistent regs).
//  - sPv float4 -> float2 (W3 only); b2 has its own tiny LDS array.
//  - A-fragments declared as uint4 so MFMA operands are born as aligned
//    quads (no per-ntl v_mov quad re-forming).
// Grid stays 1024 x 256thr @ 4 blocks/CU: total demand is exactly 16 waves/CU,
// the only clean single-generation residency (3/CU would leave a 256-block
// second generation ~= +70% time on persistent 100-step blocks).

#define W0F    44.0f
#define INV2PI 0.15915494309189535f
#define SCALE  (W0F * INV2PI)
#define WIDTH  128
#define NPART  262144
#define TSTEPS 101

typedef short s16x8 __attribute__((ext_vector_type(8)));
typedef float f32x4 __attribute__((ext_vector_type(4)));

__device__ __forceinline__ float sin_rev(float z) {
    // sin(2*pi*z); fract is the exact periodic range reduction.
    return __builtin_amdgcn_sinf(__builtin_amdgcn_fractf(z));
}
__device__ __forceinline__ unsigned short f2bf(float x) {   // RNE f32->bf16
    __bf16 b = (__bf16)x;
    return __builtin_bit_cast(unsigned short, b);
}
__device__ __forceinline__ float bf2f(unsigned short u) {   // exact bf16->f32
    unsigned int v = ((unsigned int)u) << 16;
    return __builtin_bit_cast(float, v);
}

// ---- 16-lane (DPP row) all-lanes sum via circulant row_ror adds ----
#define ROR_ADD(x, ctrl) ((x) + __builtin_bit_cast(float, \
    __builtin_amdgcn_update_dpp(0, __builtin_bit_cast(int, (x)), (ctrl), 0xF, 0xF, false)))
__device__ __forceinline__ float row_sum16(float x) {
    x = ROR_ADD(x, 0x128);   // row_ror:8
    x = ROR_ADD(x, 0x124);   // row_ror:4
    x = ROR_ADD(x, 0x122);   // row_ror:2
    x = ROR_ADD(x, 0x121);   // row_ror:1
    return x;                // every lane holds the 16-lane sum
}

// 8-way register select (7 v_cndmask), idx = per-lane 0..7
__device__ __forceinline__ float sel8(const float g[8], int idx) {
    float a[4], b[2];
    #pragma unroll
    for (int i = 0; i < 4; ++i) a[i] = (idx & 4) ? g[i + 4] : g[i];
    #pragma unroll
    for (int i = 0; i < 2; ++i) b[i] = (idx & 2) ? a[i + 2] : a[i];
    return (idx & 1) ? b[1] : b[0];
}

// ws layout: shorts [0,16384) = W2-hi B-frags; shorts [16384,32768) = W2-lo
// B-frags; floats [16384,16640) = SCALE*W1; floats [16640,16768) = SCALE*b1.
// Frag index i = ((nt*4+c)*64 + lane)*8 + j  <->  B[k][n], k=32c+8*(lane>>4)+j,
// n=16*nt+(lane&15)  (mfma_f32_16x16x32_bf16 B-operand layout).
__global__ void prep_kernel(const float* __restrict__ W1, const float* __restrict__ b1,
                            const float* __restrict__ W2, float* __restrict__ ws) {
    int i = blockIdx.x * blockDim.x + threadIdx.x;
    unsigned short* whi = (unsigned short*)ws;
    unsigned short* wlo = whi + 16384;
    if (i < 16384) {
        int j = i & 7, l = (i >> 3) & 63, c = (i >> 9) & 3, nt = (i >> 11) & 7;
        int k = 32 * c + 8 * (l >> 4) + j;
        int n = 16 * nt + (l & 15);
        float v = SCALE * W2[k * WIDTH + n];
        unsigned short hi = f2bf(v);
        whi[i] = hi;
        wlo[i] = f2bf(v - bf2f(hi));
    }
    if (i < 2 * WIDTH) ws[16384 + i] = SCALE * W1[i];
    if (i < WIDTH)     ws[16384 + 256 + i] = SCALE * b1[i];
}

__launch_bounds__(256, 4)
__global__ void ode_kernel(const float* __restrict__ t,
                           const float2* __restrict__ x0,
                           const float* __restrict__ ws,
                           const float* __restrict__ W3,
                           const float* __restrict__ b2,
                           const float* __restrict__ b3,
                           float2* __restrict__ out) {
    __shared__ unsigned int sB[8192];                     // W2-hi frags, 32 KB
    __shared__ __align__(16) float sWx[WIDTH], sWy[WIDTH], sWb[WIDTH];
    __shared__ float2 sW3[WIDTH];                         // {w3x, w3y}
    __shared__ float  sB2[WIDTH];                         // SCALE*b2

    const int tid = threadIdx.x;
    const int wave = tid >> 6;
    const int lane = tid & 63;
    const int lane15 = lane & 15;
    const int kg = lane >> 4;

    // one-time staging
    {
        const uint4* src = (const uint4*)ws;
        uint4* dst = (uint4*)sB;
        #pragma unroll
        for (int j = 0; j < 8; ++j) dst[tid + 256 * j] = src[tid + 256 * j];
    }
    if (tid < WIDTH) {
        sWx[tid] = ws[16384 + tid];
        sWy[tid] = ws[16384 + WIDTH + tid];
        sWb[tid] = ws[16384 + 256 + tid];
        sW3[tid] = make_float2(W3[2 * tid], W3[2 * tid + 1]);
        sB2[tid] = SCALE * b2[tid];
    }
    __syncthreads();   // the ONLY barrier; hot loop is barrier/fence-free

    const uint4* Blo = (const uint4*)(ws + 8192);   // W2-lo frags (global, L2-hot)

    // Ownership permutation: lane l owns local particle
    //   m(l) = 16*(lane15>>2) + 4*kg + (lane15&3)
    // so the DPP-reduced row sums land at owner lanes: owner's half bit is
    // lane15>>3, its slot in that half's gx[8] is lane&7.
    const int mloc = 16 * (lane15 >> 2) + 4 * kg + (lane15 & 3);
    const int p = blockIdx.x * 256 + wave * 64 + mloc;

    float2 y = x0[p];
    out[p] = y;   // row 0 = x0

    const float b30 = b3[0], b31 = b3[1];

    float tprev = t[0];
    #pragma unroll 1
    for (int step = 0; step < TSTEPS - 1; ++step) {
        const float tnext = t[step + 1];
        const float dt = tnext - tprev;
        tprev = tnext;

        float k1x=0.f,k1y=0.f,k2x=0.f,k2y=0.f,k3x=0.f,k3y=0.f,sx=0.f,sy=0.f;

        #pragma unroll 1
        for (int s = 0; s < 4; ++s) {
            float yinx, yiny;
            if (s == 0)      { yinx = y.x;                                 yiny = y.y; }
            else if (s == 1) { const float c1 = dt * (1.0f / 3.0f);
                               yinx = y.x + c1 * k1x;                       yiny = y.y + c1 * k1y; }
            else if (s == 2) { yinx = y.x + dt * (k2x - (1.0f/3.0f) * k1x); yiny = y.y + dt * (k2y - (1.0f/3.0f) * k1y); }
            else             { yinx = y.x + dt * (k1x - k2x + k3x);         yiny = y.y + dt * (k1y - k2y + k3y); }

            float fx = b30, fy = b31;

            // GEMM over two M-halves: acc[8nt][2mt] = 64 regs; A built ONCE
            // per element (partitioned by M, no duplication).
            #pragma unroll 1
            for (int ht = 0; ht < 2; ++ht) {
                // Broadcast this half's tile-row coords (re-shfl'd per half to
                // keep them transient): row m' = 16*(2ht+mtl) + lane15 is owned
                // by lane 16*(lane15>>2) + 4*(2ht+mtl) + (lane15&3).
                const int sbase = 16 * (lane15 >> 2) + (lane15 & 3) + 8 * ht;
                const float qxl0 = __shfl(yinx, sbase,     64);
                const float qyl0 = __shfl(yiny, sbase,     64);
                const float qxl1 = __shfl(yinx, sbase + 4, 64);
                const float qyl1 = __shfl(yiny, sbase + 4, 64);

                // acc init = SCALE*b2[n] (folds the pre-sin bias add; values
                // read from LDS, no persistent registers).
                f32x4 acc[8][2];
                #pragma unroll
                for (int i = 0; i < 8; ++i) {
                    const float bb = sB2[16 * i + lane15];
                    const f32x4 v4 = (f32x4){bb, bb, bb, bb};
                    acc[i][0] = v4;
                    acc[i][1] = v4;
                }

                #pragma unroll 1
                for (int c = 0; c < 4; ++c) {
                    // Build A-fragments in-layout as aligned quads: element j
                    // of frag (mtl,c) is A[16*(2ht+mtl)+lane15][32c+8kg+j].
                    uint4 ah[2], al[2];
                    #pragma unroll
                    for (int jq = 0; jq < 2; ++jq) {
                        float4 wxv = *(const float4*)&sWx[32 * c + 8 * kg + 4 * jq];
                        float4 wyv = *(const float4*)&sWy[32 * c + 8 * kg + 4 * jq];
                        float4 wbv = *(const float4*)&sWb[32 * c + 8 * kg + 4 * jq];
                        #pragma unroll
                        for (int mtl = 0; mtl < 2; ++mtl) {
                            const float qxm = mtl ? qxl1 : qxl0;
                            const float qym = mtl ? qyl1 : qyl0;
                            float v0 = sin_rev(fmaf(qxm, wxv.x, fmaf(qym, wyv.x, wbv.x)));
                            float v1 = sin_rev(fmaf(qxm, wxv.y, fmaf(qym, wyv.y, wbv.y)));
                            float v2 = sin_rev(fmaf(qxm, wxv.z, fmaf(qym, wyv.z, wbv.z)));
                            float v3 = sin_rev(fmaf(qxm, wxv.w, fmaf(qym, wyv.w, wbv.w)));
                            unsigned short h0 = f2bf(v0), h1 = f2bf(v1);
                            unsigned short h2 = f2bf(v2), h3 = f2bf(v3);
                            unsigned int hA = (unsigned int)h0 | ((unsigned int)h1 << 16);
                            unsigned int hB = (unsigned int)h2 | ((unsigned int)h3 << 16);
                            unsigned int lA = (unsigned int)f2bf(v0 - bf2f(h0)) |
                                              ((unsigned int)f2bf(v1 - bf2f(h1)) << 16);
                            unsigned int lB = (unsigned int)f2bf(v2 - bf2f(h2)) |
                                              ((unsigned int)f2bf(v3 - bf2f(h3)) << 16);
                            if (jq == 0) { ah[mtl].x = hA; ah[mtl].y = hB;
                                           al[mtl].x = lA; al[mtl].y = lB; }
                            else         { ah[mtl].z = hA; ah[mtl].w = hB;
                                           al[mtl].z = lA; al[mtl].w = lB; }
                        }
                    }

                    // Full-N sweep for this half; lo-B prefetched in 2 batches.
                    #pragma unroll
                    for (int g = 0; g < 2; ++g) {
                        uint4 blU[4];
                        #pragma unroll
                        for (int q = 0; q < 4; ++q)
                            blU[q] = Blo[((4 * g + q) * 4 + c) * 64 + lane];
                        #pragma unroll
                        for (int q = 0; q < 4; ++q) {
                            const int ntl = 4 * g + q;
                            uint4 bhU = *(const uint4*)&sB[(ntl * 4 + c) * 256 + lane * 4];
                            s16x8 bh = __builtin_bit_cast(s16x8, bhU);
                            s16x8 bl = __builtin_bit_cast(s16x8, blU[q]);
                            #pragma unroll
                            for (int mtl = 0; mtl < 2; ++mtl) {
                                s16x8 ahv = __builtin_bit_cast(s16x8, ah[mtl]);
                                s16x8 alv = __builtin_bit_cast(s16x8, al[mtl]);
                                acc[ntl][mtl] = __builtin_amdgcn_mfma_f32_16x16x32_bf16(ahv, bh, acc[ntl][mtl], 0, 0, 0);
                                acc[ntl][mtl] = __builtin_amdgcn_mfma_f32_16x16x32_bf16(alv, bh, acc[ntl][mtl], 0, 0, 0);
                                acc[ntl][mtl] = __builtin_amdgcn_mfma_f32_16x16x32_bf16(ahv, bl, acc[ntl][mtl], 0, 0, 0);
                            }
                        }
                    }
                }

                // Epilogue: sin + layer-3 column partials for this M-half.
                // C layout: value (ntl,mtl,r) = row 16*(2ht+mtl)+4kg+r,
                // col n = 16*ntl + lane15. (b2 already inside acc.)
                float gx[8], gy[8];
                #pragma unroll
                for (int i = 0; i < 8; ++i) { gx[i] = 0.f; gy[i] = 0.f; }
                #pragma unroll
                for (int ntl = 0; ntl < 8; ++ntl) {
                    float2 w3v = sW3[16 * ntl + lane15];
                    #pragma unroll
                    for (int mtl = 0; mtl < 2; ++mtl) {
                        #pragma unroll
                        for (int r = 0; r < 4; ++r) {
                            float sn = sin_rev(acc[ntl][mtl][r]);
                            gx[4*mtl+r] = fmaf(sn, w3v.x, gx[4*mtl+r]);
                            gy[4*mtl+r] = fmaf(sn, w3v.y, gy[4*mtl+r]);
                        }
                    }
                }
                // 16-lane n-reduction (DPP, no LDS); owner select.
                #pragma unroll
                for (int i = 0; i < 8; ++i) { gx[i] = row_sum16(gx[i]); gy[i] = row_sum16(gy[i]); }
                const float vx = sel8(gx, lane & 7);
                const float vy = sel8(gy, lane & 7);
                const bool own = ((lane15 >> 3) == ht);
                fx += own ? vx : 0.0f;
                fy += own ? vy : 0.0f;
            }
            // ---- end f ----

            if (s == 0)      { k1x = fx; k1y = fy; sx = fx;        sy = fy; }
            else if (s == 1) { k2x = fx; k2y = fy; sx += 3.f * fx; sy += 3.f * fy; }
            else if (s == 2) { k3x = fx; k3y = fy; sx += 3.f * fx; sy += 3.f * fy; }
            else             {                     sx += fx;       sy += fy; }
        }

        const float cc = dt * 0.125f;
        y.x += sx * cc;
        y.y += sy * cc;
        out[(size_t)(step + 1) * NPART + p] = y;
    }
}

extern "C" void kernel_launch(void* const* d_in, const int* in_sizes, int n_in,
                              void* d_out, int out_size, void* d_ws, size_t ws_size,
                              hipStream_t stream) {
    const float*  t  = (const float*)d_in[0];
    const float2* x0 = (const float2*)d_in[1];
    const float*  W1 = (const float*)d_in[2];
    const float*  b1 = (const float*)d_in[3];
    const float*  W2 = (const float*)d_in[4];
    const float*  b2 = (const float*)d_in[5];
    const float*  W3 = (const float*)d_in[6];
    const float*  b3 = (const float*)d_in[7];
    float* ws = (float*)d_ws;
    float2* out = (float2*)d_out;

    prep_kernel<<<64, 256, 0, stream>>>(W1, b1, W2, ws);
    ode_kernel<<<NPART / 256, 256, 0, stream>>>(t, x0, ws, W3, b2, b3, out);
}

// Round 4
// 10424.049 us; speedup vs baseline: 1.9147x; 1.2877x over previous
//
#include <hip/hip_runtime.h>

// NeuralODE SIREN (2->128->128->2, sin, w0=44), RK4 3/8-rule, 100 steps.
// Round 6: the 128-reg/4-block budget was structurally impossible (acc=64 AGPR
// leaves ~64 arch VGPRs vs ~80+ needed -> ~20 dwords/f-eval hot-loop scratch =
// the stubborn 8.4 GB WRITE_SIZE). Trade occupancy for registers:
//  - __launch_bounds__(256, 2): 256 unified regs/wave, ZERO spill.
//  - W2-lo moves into LDS next to W2-hi (68.6 KB/block, 2 blocks/CU fits
//    137 KB < 160 KB): the hot loop touches NO global memory except the
//    out store. No Blo L2-miss stalls, no scratch traffic.
//  - Full-M GEMM returns (acc[8][4] = 128 AGPRs): B read once per c (16
//    ds_read_b128), A built once, single epilogue + DPP reduction pass
//    (sel16(gx, lane15) -- the round-2-verified owner mapping).
//  - 2 waves/SIMD latency hiding: per-c fully-unrolled nt-loop lets the
//    compiler hoist all 16 ds_reads; MFMA(wave A) overlaps VALU(wave B).

#define W0F    44.0f
#define INV2PI 0.15915494309189535f
#define SCALE  (W0F * INV2PI)
#define WIDTH  128
#define NPART  262144
#define TSTEPS 101

typedef short s16x8 __attribute__((ext_vector_type(8)));
typedef float f32x4 __attribute__((ext_vector_type(4)));

__device__ __forceinline__ float sin_rev(float z) {
    // sin(2*pi*z); fract is the exact periodic range reduction.
    return __builtin_amdgcn_sinf(__builtin_amdgcn_fractf(z));
}
__device__ __forceinline__ unsigned short f2bf(float x) {   // RNE f32->bf16
    __bf16 b = (__bf16)x;
    return __builtin_bit_cast(unsigned short, b);
}
__device__ __forceinline__ float bf2f(unsigned short u) {   // exact bf16->f32
    unsigned int v = ((unsigned int)u) << 16;
    return __builtin_bit_cast(float, v);
}

// ---- 16-lane (DPP row) all-lanes sum via circulant row_ror adds ----
#define ROR_ADD(x, ctrl) ((x) + __builtin_bit_cast(float, \
    __builtin_amdgcn_update_dpp(0, __builtin_bit_cast(int, (x)), (ctrl), 0xF, 0xF, false)))
__device__ __forceinline__ float row_sum16(float x) {
    x = ROR_ADD(x, 0x128);   // row_ror:8
    x = ROR_ADD(x, 0x124);   // row_ror:4
    x = ROR_ADD(x, 0x122);   // row_ror:2
    x = ROR_ADD(x, 0x121);   // row_ror:1
    return x;                // every lane holds the 16-lane sum
}

// 16-way register select (15 v_cndmask), idx = per-lane 0..15
__device__ __forceinline__ float sel16(const float g[16], int idx) {
    float a[8], b[4], c[2];
    #pragma unroll
    for (int i = 0; i < 8; ++i) a[i] = (idx & 8) ? g[i + 8] : g[i];
    #pragma unroll
    for (int i = 0; i < 4; ++i) b[i] = (idx & 4) ? a[i + 4] : a[i];
    #pragma unroll
    for (int i = 0; i < 2; ++i) c[i] = (idx & 2) ? b[i + 2] : b[i];
    return (idx & 1) ? c[1] : c[0];
}

// ws layout: shorts [0,16384) = W2-hi B-frags; shorts [16384,32768) = W2-lo
// B-frags; floats [16384,16640) = SCALE*W1; floats [16640,16768) = SCALE*b1.
// Frag index i = ((nt*4+c)*64 + lane)*8 + j  <->  B[k][n], k=32c+8*(lane>>4)+j,
// n=16*nt+(lane&15)  (mfma_f32_16x16x32_bf16 B-operand layout).
__global__ void prep_kernel(const float* __restrict__ W1, const float* __restrict__ b1,
                            const float* __restrict__ W2, float* __restrict__ ws) {
    int i = blockIdx.x * blockDim.x + threadIdx.x;
    unsigned short* whi = (unsigned short*)ws;
    unsigned short* wlo = whi + 16384;
    if (i < 16384) {
        int j = i & 7, l = (i >> 3) & 63, c = (i >> 9) & 3, nt = (i >> 11) & 7;
        int k = 32 * c + 8 * (l >> 4) + j;
        int n = 16 * nt + (l & 15);
        float v = SCALE * W2[k * WIDTH + n];
        unsigned short hi = f2bf(v);
        whi[i] = hi;
        wlo[i] = f2bf(v - bf2f(hi));
    }
    if (i < 2 * WIDTH) ws[16384 + i] = SCALE * W1[i];
    if (i < WIDTH)     ws[16384 + 256 + i] = SCALE * b1[i];
}

__launch_bounds__(256, 2)
__global__ void ode_kernel(const float* __restrict__ t,
                           const float2* __restrict__ x0,
                           const float* __restrict__ ws,
                           const float* __restrict__ W3,
                           const float* __restrict__ b2,
                           const float* __restrict__ b3,
                           float2* __restrict__ out) {
    __shared__ unsigned int sBh[8192];                    // W2-hi frags, 32 KB
    __shared__ unsigned int sBl[8192];                    // W2-lo frags, 32 KB
    __shared__ __align__(16) float sWx[WIDTH], sWy[WIDTH], sWb[WIDTH];
    __shared__ float2 sW3[WIDTH];                         // {w3x, w3y}
    __shared__ float  sB2[WIDTH];                         // SCALE*b2

    const int tid = threadIdx.x;
    const int wave = tid >> 6;
    const int lane = tid & 63;
    const int lane15 = lane & 15;
    const int kg = lane >> 4;

    // one-time staging (hi + lo fragment banks)
    {
        const uint4* srch = (const uint4*)ws;
        const uint4* srcl = (const uint4*)(ws + 8192);
        uint4* dsth = (uint4*)sBh;
        uint4* dstl = (uint4*)sBl;
        #pragma unroll
        for (int j = 0; j < 8; ++j) {
            dsth[tid + 256 * j] = srch[tid + 256 * j];
            dstl[tid + 256 * j] = srcl[tid + 256 * j];
        }
    }
    if (tid < WIDTH) {
        sWx[tid] = ws[16384 + tid];
        sWy[tid] = ws[16384 + WIDTH + tid];
        sWb[tid] = ws[16384 + 256 + tid];
        sW3[tid] = make_float2(W3[2 * tid], W3[2 * tid + 1]);
        sB2[tid] = SCALE * b2[tid];
    }
    __syncthreads();   // the ONLY barrier; hot loop is barrier/fence-free

    // Ownership permutation: lane l owns local particle
    //   m(l) = 16*(lane15>>2) + 4*kg + (lane15&3)
    // so the DPP-reduced row sums land at owner lanes: owner's gx slot is
    // 4*(lane15>>2) + (lane15&3) == lane15.
    const int mloc = 16 * (lane15 >> 2) + 4 * kg + (lane15 & 3);
    const int p = blockIdx.x * 256 + wave * 64 + mloc;

    float2 y = x0[p];
    out[p] = y;   // row 0 = x0

    const float b30 = b3[0], b31 = b3[1];

    float tprev = t[0];
    #pragma unroll 1
    for (int step = 0; step < TSTEPS - 1; ++step) {
        const float tnext = t[step + 1];
        const float dt = tnext - tprev;
        tprev = tnext;

        float k1x=0.f,k1y=0.f,k2x=0.f,k2y=0.f,k3x=0.f,k3y=0.f,sx=0.f,sy=0.f;

        #pragma unroll 1
        for (int s = 0; s < 4; ++s) {
            float yinx, yiny;
            if (s == 0)      { yinx = y.x;                                 yiny = y.y; }
            else if (s == 1) { const float c1 = dt * (1.0f / 3.0f);
                               yinx = y.x + c1 * k1x;                       yiny = y.y + c1 * k1y; }
            else if (s == 2) { yinx = y.x + dt * (k2x - (1.0f/3.0f) * k1x); yiny = y.y + dt * (k2y - (1.0f/3.0f) * k1y); }
            else             { yinx = y.x + dt * (k1x - k2x + k3x);         yiny = y.y + dt * (k1y - k2y + k3y); }

            // ---- f(yin) ----
            // Broadcast tile-row coords: row m' = 16*mt + lane15 is owned by
            // lane 16*(lane15>>2) + 4*mt + (lane15&3).
            float qx[4], qy[4];
            {
                const int sbase = 16 * (lane15 >> 2) + (lane15 & 3);
                qx[0] = __shfl(yinx, sbase,      64); qy[0] = __shfl(yiny, sbase,      64);
                qx[1] = __shfl(yinx, sbase + 4,  64); qy[1] = __shfl(yiny, sbase + 4,  64);
                qx[2] = __shfl(yinx, sbase + 8,  64); qy[2] = __shfl(yiny, sbase + 8,  64);
                qx[3] = __shfl(yinx, sbase + 12, 64); qy[3] = __shfl(yiny, sbase + 12, 64);
            }

            // Full-M, full-N GEMM: acc[8nt][4mt] = 128 AGPRs, init = SCALE*b2.
            f32x4 acc[8][4];
            #pragma unroll
            for (int i = 0; i < 8; ++i) {
                const float bb = sB2[16 * i + lane15];
                const f32x4 v4 = (f32x4){bb, bb, bb, bb};
                #pragma unroll
                for (int mt = 0; mt < 4; ++mt) acc[i][mt] = v4;
            }

            #pragma unroll 1
            for (int c = 0; c < 4; ++c) {
                // Build A-fragments in-layout as aligned quads: element j of
                // frag (mt,c) is A[16*mt+lane15][32c+8kg+j].
                uint4 ah[4], al[4];
                #pragma unroll
                for (int jq = 0; jq < 2; ++jq) {
                    float4 wxv = *(const float4*)&sWx[32 * c + 8 * kg + 4 * jq];
                    float4 wyv = *(const float4*)&sWy[32 * c + 8 * kg + 4 * jq];
                    float4 wbv = *(const float4*)&sWb[32 * c + 8 * kg + 4 * jq];
                    #pragma unroll
                    for (int mt = 0; mt < 4; ++mt) {
                        float v0 = sin_rev(fmaf(qx[mt], wxv.x, fmaf(qy[mt], wyv.x, wbv.x)));
                        float v1 = sin_rev(fmaf(qx[mt], wxv.y, fmaf(qy[mt], wyv.y, wbv.y)));
                        float v2 = sin_rev(fmaf(qx[mt], wxv.z, fmaf(qy[mt], wyv.z, wbv.z)));
                        float v3 = sin_rev(fmaf(qx[mt], wxv.w, fmaf(qy[mt], wyv.w, wbv.w)));
                        unsigned short h0 = f2bf(v0), h1 = f2bf(v1);
                        unsigned short h2 = f2bf(v2), h3 = f2bf(v3);
                        unsigned int hA = (unsigned int)h0 | ((unsigned int)h1 << 16);
                        unsigned int hB = (unsigned int)h2 | ((unsigned int)h3 << 16);
                        unsigned int lA = (unsigned int)f2bf(v0 - bf2f(h0)) |
                                          ((unsigned int)f2bf(v1 - bf2f(h1)) << 16);
                        unsigned int lB = (unsigned int)f2bf(v2 - bf2f(h2)) |
                                          ((unsigned int)f2bf(v3 - bf2f(h3)) << 16);
                        if (jq == 0) { ah[mt].x = hA; ah[mt].y = hB;
                                       al[mt].x = lA; al[mt].y = lB; }
                        else         { ah[mt].z = hA; ah[mt].w = hB;
                                       al[mt].z = lA; al[mt].w = lB; }
                    }
                }

                // Full-N sweep, B from LDS only (hi and lo banks).
                #pragma unroll
                for (int nt = 0; nt < 8; ++nt) {
                    const int fo = (nt * 4 + c) * 256 + lane * 4;
                    uint4 bhU = *(const uint4*)&sBh[fo];
                    uint4 blU = *(const uint4*)&sBl[fo];
                    s16x8 bh = __builtin_bit_cast(s16x8, bhU);
                    s16x8 bl = __builtin_bit_cast(s16x8, blU);
                    #pragma unroll
                    for (int mt = 0; mt < 4; ++mt) {
                        s16x8 ahv = __builtin_bit_cast(s16x8, ah[mt]);
                        s16x8 alv = __builtin_bit_cast(s16x8, al[mt]);
                        acc[nt][mt] = __builtin_amdgcn_mfma_f32_16x16x32_bf16(ahv, bh, acc[nt][mt], 0, 0, 0);
                        acc[nt][mt] = __builtin_amdgcn_mfma_f32_16x16x32_bf16(alv, bh, acc[nt][mt], 0, 0, 0);
                        acc[nt][mt] = __builtin_amdgcn_mfma_f32_16x16x32_bf16(ahv, bl, acc[nt][mt], 0, 0, 0);
                    }
                }
            }

            // Epilogue: sin + layer-3 column partials (b2 already in acc).
            // C layout: value (nt,mt,r) = row 16*mt+4*kg+r, col 16*nt+lane15.
            float gx[16], gy[16];
            #pragma unroll
            for (int i = 0; i < 16; ++i) { gx[i] = 0.f; gy[i] = 0.f; }
            #pragma unroll
            for (int nt = 0; nt < 8; ++nt) {
                float2 w3v = sW3[16 * nt + lane15];
                #pragma unroll
                for (int mt = 0; mt < 4; ++mt) {
                    #pragma unroll
                    for (int r = 0; r < 4; ++r) {
                        float sn = sin_rev(acc[nt][mt][r]);
                        gx[4*mt+r] = fmaf(sn, w3v.x, gx[4*mt+r]);
                        gy[4*mt+r] = fmaf(sn, w3v.y, gy[4*mt+r]);
                    }
                }
            }
            // 16-lane n-reduction (DPP, no LDS); owner slot is lane15.
            #pragma unroll
            for (int i = 0; i < 16; ++i) { gx[i] = row_sum16(gx[i]); gy[i] = row_sum16(gy[i]); }
            const float fx = b30 + sel16(gx, lane15);
            const float fy = b31 + sel16(gy, lane15);
            // ---- end f ----

            if (s == 0)      { k1x = fx; k1y = fy; sx = fx;        sy = fy; }
            else if (s == 1) { k2x = fx; k2y = fy; sx += 3.f * fx; sy += 3.f * fy; }
            else if (s == 2) { k3x = fx; k3y = fy; sx += 3.f * fx; sy += 3.f * fy; }
            else             {                     sx += fx;       sy += fy; }
        }

        const float cc = dt * 0.125f;
        y.x += sx * cc;
        y.y += sy * cc;
        out[(size_t)(step + 1) * NPART + p] = y;
    }
}

extern "C" void kernel_launch(void* const* d_in, const int* in_sizes, int n_in,
                              void* d_out, int out_size, void* d_ws, size_t ws_size,
                              hipStream_t stream) {
    const float*  t  = (const float*)d_in[0];
    const float2* x0 = (const float2*)d_in[1];
    const float*  W1 = (const float*)d_in[2];
    const float*  b1 = (const float*)d_in[3];
    const float*  W2 = (const float*)d_in[4];
    const float*  b2 = (const float*)d_in[5];
    const float*  W3 = (const float*)d_in[6];
    const float*  b3 = (const float*)d_in[7];
    float* ws = (float*)d_ws;
    float2* out = (float2*)d_out;

    prep_kernel<<<64, 256, 0, stream>>>(W1, b1, W2, ws);
    ode_kernel<<<NPART / 256, 256, 0, stream>>>(t, x0, ws, W3, b2, b3, out);
}